// Round 1
// baseline (334.491 us; speedup 1.0000x reference)
//
#include <hip/hip_runtime.h>
#include <stdint.h>

#define S_LEN  8192
#define G_LEN  128
#define E_DIM  1024
#define H_NUM  16
#define BS_LEN 512
#define R_TOT  8320          // G + S total rows
#define KBLK   128           // 1024/8 k-blocks
#define XBLK   1040          // R_TOT/8
#define NSPL   10            // global-attn key splits
#define SPLW   832           // keys per split (26 chunks of 32)

typedef _Float16 half8    __attribute__((ext_vector_type(8)));
typedef float    floatx4  __attribute__((ext_vector_type(4)));
typedef float    floatx16 __attribute__((ext_vector_type(16)));

// ---- workspace layout (bytes); total ~81.9 MB ----
#define OFF_XP   0
#define OFF_AOP  0            // reuse: Xp dead after QKV GEMM
#define OFF_WP   17039360
#define SZ_WP1   2097152
#define OFF_QP   25427968
#define OFF_KP   42467328
#define OFF_VP   59506688
#define OFF_MASK 76546048
#define OFF_OG   76579328
#define OFF_LG   81822208

__device__ __forceinline__ floatx16 zero16() {
  floatx16 v;
#pragma unroll
  for (int i = 0; i < 16; ++i) v[i] = 0.0f;
  return v;
}
__device__ __forceinline__ floatx4 zero4() {
  floatx4 v;
#pragma unroll
  for (int i = 0; i < 4; ++i) v[i] = 0.0f;
  return v;
}

// async global->LDS, 16B per lane; lds dst is wave-uniform base + lane*16
__device__ __forceinline__ void gl_lds16(const void* g, void* l) {
  __builtin_amdgcn_global_load_lds(
      (const __attribute__((address_space(1))) void*)g,
      (__attribute__((address_space(3))) void*)l, 16, 0, 0);
}

// ---------------- stage 0: pack X (f32 -> f16, k-block-packed) ----------------
// Xp[kb][r][j] = X_all[r][8*kb + j],  X_all = [global(128) ; token(8192)]
__global__ void pack_x_k(const float* __restrict__ tok,
                         const float* __restrict__ glob,
                         char* __restrict__ ws) {
  int t = blockIdx.x * 256 + threadIdx.x;       // t = kb*R_TOT + r
  if (t >= KBLK * R_TOT) return;
  int kb = t / R_TOT;
  int r  = t - kb * R_TOT;
  const float* src = (r < G_LEN) ? (glob + (size_t)r * E_DIM)
                                 : (tok + (size_t)(r - G_LEN) * E_DIM);
  float4 a = *(const float4*)&src[kb * 8];
  float4 b = *(const float4*)&src[kb * 8 + 4];
  half8 v;
  v[0] = (_Float16)a.x; v[1] = (_Float16)a.y; v[2] = (_Float16)a.z; v[3] = (_Float16)a.w;
  v[4] = (_Float16)b.x; v[5] = (_Float16)b.y; v[6] = (_Float16)b.z; v[7] = (_Float16)b.w;
  *(half8*)((_Float16*)(ws + OFF_XP) + (size_t)t * 8) = v;
}

// -------- stage 0b: pack W (transposed, k-block-packed) + ext mask --------
// Wp[w][kb][n][j] = W[8*kb+j][n];  emask[r] = 0 (r<G) else mask[r-G]
__global__ void pack_w_k(const float* __restrict__ Wq, const float* __restrict__ Wk,
                         const float* __restrict__ Wv, const float* __restrict__ Wo,
                         const float* __restrict__ mask, char* __restrict__ ws) {
  int t = blockIdx.x * 256 + threadIdx.x;
  const int NW = 4 * KBLK * 1024;
  if (t < NW) {
    int w   = t >> 17;            // KBLK*1024 = 131072
    int rem = t & 131071;
    int kb  = rem >> 10;
    int n   = rem & 1023;
    const float* W = (w == 0) ? Wq : (w == 1) ? Wk : (w == 2) ? Wv : Wo;
    half8 v;
#pragma unroll
    for (int j = 0; j < 8; ++j)
      v[j] = (_Float16)W[(size_t)(kb * 8 + j) * 1024 + n];
    *(half8*)(ws + OFF_WP + (size_t)w * SZ_WP1 + (size_t)(kb * 1024 + n) * 16) = v;
  } else {
    int t2 = t - NW;
    if (t2 < R_TOT) {
      float* em = (float*)(ws + OFF_MASK);
      em[t2] = (t2 < G_LEN) ? 0.0f : mask[t2 - G_LEN];
    }
  }
}

// ---------------- shared GEMM mainloop: C128x128 = A[8320xK] * B[1024-col] ----------------
// A source: packed [kb][R_TOT][8]; B source: packed [kb][1024][8]; 16 K-steps of 64.
__device__ __forceinline__ void gemm_tile(const _Float16* __restrict__ Ap,
                                          const _Float16* __restrict__ Bp,
                                          int m0, int n0, _Float16* lds,
                                          floatx4 acc[4][4]) {
  const int tid  = threadIdx.x;
  const int wave = tid >> 6;
  const int lane = tid & 63;
  const int quad = lane >> 4;
  const int l16  = lane & 15;
  _Float16* As = lds;
  _Float16* Bs = lds + 8 * 128 * 8;
  const int wm = (wave >> 1) * 64;
  const int wn = (wave & 1) * 64;
  for (int step = 0; step < 16; ++step) {
#pragma unroll
    for (int ui = 0; ui < 8; ++ui) {
      const int u   = wave * 8 + ui;   // 32 load units: 16 A, 16 B
      const int isB = u >> 4;
      const int vv  = u & 15;
      const int kb  = vv >> 1;
      const int rh  = vv & 1;
      const _Float16* src =
          isB ? Bp + (size_t)((step * 8 + kb) * 1024 + n0 + rh * 64 + lane) * 8
              : Ap + (size_t)((step * 8 + kb) * R_TOT + m0 + rh * 64 + lane) * 8;
      _Float16* dst = (isB ? Bs : As) + (kb * 128 + rh * 64) * 8;
      gl_lds16(src, dst);
    }
    __syncthreads();
#pragma unroll
    for (int kk = 0; kk < 2; ++kk) {
      half8 af[4], bf[4];
#pragma unroll
      for (int mt = 0; mt < 4; ++mt)
        af[mt] = *(const half8*)(As + ((kk * 4 + quad) * 128 + wm + mt * 16 + l16) * 8);
#pragma unroll
      for (int nt = 0; nt < 4; ++nt)
        bf[nt] = *(const half8*)(Bs + ((kk * 4 + quad) * 128 + wn + nt * 16 + l16) * 8);
#pragma unroll
      for (int mt = 0; mt < 4; ++mt)
#pragma unroll
        for (int nt = 0; nt < 4; ++nt)
          acc[mt][nt] = __builtin_amdgcn_mfma_f32_16x16x32_f16(af[mt], bf[nt], acc[mt][nt], 0, 0, 0);
    }
    __syncthreads();
  }
}

// ---------------- stage 1: QKV projections ----------------
// z=0: Q (scaled 0.125) -> Qp[h][db][r][j]; z=1: K -> Kp same; z=2: V -> Vp[h][xb][d][j]
__global__ __launch_bounds__(256) void qkv_gemm_k(char* __restrict__ ws) {
  __shared__ __align__(16) _Float16 lds[2 * 8 * 128 * 8];
  const int z  = blockIdx.z;
  const int m0 = blockIdx.y * 128;
  const int n0 = blockIdx.x * 128;
  const _Float16* Ap = (const _Float16*)(ws + OFF_XP);
  const _Float16* Bp = (const _Float16*)(ws + OFF_WP + (size_t)z * SZ_WP1);
  _Float16* dst = (_Float16*)(ws + (z == 0 ? OFF_QP : (z == 1 ? OFF_KP : OFF_VP)));
  floatx4 acc[4][4];
#pragma unroll
  for (int a = 0; a < 4; ++a)
#pragma unroll
    for (int b = 0; b < 4; ++b) acc[a][b] = zero4();
  gemm_tile(Ap, Bp, m0, n0, lds, acc);

  const int lane = threadIdx.x & 63, wave = threadIdx.x >> 6;
  const int quad = lane >> 4, l16 = lane & 15;
  const int wm = (wave >> 1) * 64, wn = (wave & 1) * 64;
  const float scale = (z == 0) ? 0.125f : 1.0f;
#pragma unroll
  for (int mt = 0; mt < 4; ++mt)
#pragma unroll
    for (int nt = 0; nt < 4; ++nt)
#pragma unroll
      for (int r = 0; r < 4; ++r) {
        int m = m0 + wm + mt * 16 + quad * 4 + r;
        int n = n0 + wn + nt * 16 + l16;
        float c = acc[mt][nt][r] * scale;
        int idx;
        if (z < 2) idx = (((n >> 6) * 8 + ((n & 63) >> 3)) * R_TOT + m) * 8 + (n & 7);
        else       idx = (((n >> 6) * XBLK + (m >> 3)) * 64 + (n & 63)) * 8 + (m & 7);
        dst[idx] = (_Float16)c;
      }
}

// ---------------- fused attention core ----------------
// one wave = 32 queries (32x32x16 mfma). No max-subtraction (logits ~ +-3).
// l (row-sum) accumulated via mfma against all-ones B fragment.
__device__ __forceinline__ void attn_chunks(const _Float16* __restrict__ Kph,
                                            const _Float16* __restrict__ Vph,
                                            const float* __restrict__ em,
                                            const half8 qa[4], int lane,
                                            int kbase0, int nch, _Float16* pb,
                                            floatx16& o0, floatx16& o1, floatx16& lacc,
                                            half8 ones) {
  const int half_ = lane >> 5;
  const int c     = lane & 31;
  for (int ci = 0; ci < nch; ++ci) {
    const int kb = kbase0 + ci * 32;
    floatx16 s = zero16();
#pragma unroll
    for (int ks = 0; ks < 4; ++ks) {
      half8 bfr = *(const half8*)&Kph[(size_t)((ks * 2 + half_) * R_TOT + kb + c) * 8];
      s = __builtin_amdgcn_mfma_f32_32x32x16_f16(qa[ks], bfr, s, 0, 0, 0);
    }
    const float mval = em[kb + c];
#pragma unroll
    for (int r = 0; r < 16; ++r) {
      float p = __expf(s[r] + mval);
      int row = (r & 3) + ((r >> 2) << 3) + (half_ << 2);
      pb[row * 40 + c] = (_Float16)p;   // C-layout -> LDS (stride 40: 16B-aligned rows)
    }
    __asm__ __volatile__("s_waitcnt lgkmcnt(0)" ::: "memory");
    half8 pa0 = *(const half8*)&pb[c * 40 + half_ * 8];        // P A-frag, keys 0..15
    half8 pa1 = *(const half8*)&pb[c * 40 + 16 + half_ * 8];   // keys 16..31
    lacc = __builtin_amdgcn_mfma_f32_32x32x16_f16(pa0, ones, lacc, 0, 0, 0);
    lacc = __builtin_amdgcn_mfma_f32_32x32x16_f16(pa1, ones, lacc, 0, 0, 0);
    const int xb = kb >> 3;
    half8 v00 = *(const half8*)&Vph[(size_t)((xb + half_) * 64 + c) * 8];
    half8 v01 = *(const half8*)&Vph[(size_t)((xb + half_) * 64 + 32 + c) * 8];
    half8 v10 = *(const half8*)&Vph[(size_t)((xb + 2 + half_) * 64 + c) * 8];
    half8 v11 = *(const half8*)&Vph[(size_t)((xb + 2 + half_) * 64 + 32 + c) * 8];
    o0 = __builtin_amdgcn_mfma_f32_32x32x16_f16(pa0, v00, o0, 0, 0, 0);
    o0 = __builtin_amdgcn_mfma_f32_32x32x16_f16(pa1, v10, o0, 0, 0, 0);
    o1 = __builtin_amdgcn_mfma_f32_32x32x16_f16(pa0, v01, o1, 0, 0, 0);
    o1 = __builtin_amdgcn_mfma_f32_32x32x16_f16(pa1, v11, o1, 0, 0, 0);
  }
}

__device__ __forceinline__ half8 ones8() {
  half8 v;
#pragma unroll
  for (int i = 0; i < 8; ++i) v[i] = (_Float16)1.0f;
  return v;
}

// ---------------- stage 2a: local attention ----------------
__global__ __launch_bounds__(256) void local_attn_k(char* __restrict__ ws) {
  __shared__ __align__(16) _Float16 pbuf[4][32 * 40];
  const int wave = threadIdx.x >> 6, lane = threadIdx.x & 63;
  const int h = blockIdx.z, blk = blockIdx.y, qg = blockIdx.x;
  const int qbase = G_LEN + blk * BS_LEN + qg * 128 + wave * 32;
  const _Float16* Qph = (const _Float16*)(ws + OFF_QP) + (size_t)h * 8 * R_TOT * 8;
  const _Float16* Kph = (const _Float16*)(ws + OFF_KP) + (size_t)h * 8 * R_TOT * 8;
  const _Float16* Vph = (const _Float16*)(ws + OFF_VP) + (size_t)h * XBLK * 64 * 8;
  const float* em = (const float*)(ws + OFF_MASK);
  const int half_ = lane >> 5, c = lane & 31;
  half8 qa[4];
#pragma unroll
  for (int ks = 0; ks < 4; ++ks)
    qa[ks] = *(const half8*)&Qph[(size_t)((ks * 2 + half_) * R_TOT + qbase + c) * 8];
  floatx16 o0 = zero16(), o1 = zero16(), l = zero16();
  half8 ones = ones8();
  attn_chunks(Kph, Vph, em, qa, lane, 0, G_LEN / 32, pbuf[wave], o0, o1, l, ones);
  attn_chunks(Kph, Vph, em, qa, lane, G_LEN + blk * BS_LEN, BS_LEN / 32, pbuf[wave], o0, o1, l, ones);
  _Float16* AOp = (_Float16*)(ws + OFF_AOP);
#pragma unroll
  for (int r = 0; r < 16; ++r) {
    int row = (r & 3) + ((r >> 2) << 3) + (half_ << 2);
    float inv = 1.0f / l[r];
    int m  = qbase + row;
    int n0 = h * 64 + c;
    int n1 = h * 64 + 32 + c;
    AOp[((n0 >> 3) * R_TOT + m) * 8 + (n0 & 7)] = (_Float16)(o0[r] * inv);
    AOp[((n1 >> 3) * R_TOT + m) * 8 + (n1 & 7)] = (_Float16)(o1[r] * inv);
  }
}

// ---------------- stage 2b: global attention (key-split partials) ----------------
__global__ __launch_bounds__(256) void global_attn_k(char* __restrict__ ws) {
  __shared__ __align__(16) _Float16 pbuf[4][32 * 40];
  const int wave = threadIdx.x >> 6, lane = threadIdx.x & 63;
  const int spl = blockIdx.x, h = blockIdx.y;
  const int qbase = wave * 32;                       // global queries = rows 0..127
  const _Float16* Qph = (const _Float16*)(ws + OFF_QP) + (size_t)h * 8 * R_TOT * 8;
  const _Float16* Kph = (const _Float16*)(ws + OFF_KP) + (size_t)h * 8 * R_TOT * 8;
  const _Float16* Vph = (const _Float16*)(ws + OFF_VP) + (size_t)h * XBLK * 64 * 8;
  const float* em = (const float*)(ws + OFF_MASK);
  const int half_ = lane >> 5, c = lane & 31;
  half8 qa[4];
#pragma unroll
  for (int ks = 0; ks < 4; ++ks)
    qa[ks] = *(const half8*)&Qph[(size_t)((ks * 2 + half_) * R_TOT + qbase + c) * 8];
  floatx16 o0 = zero16(), o1 = zero16(), l = zero16();
  half8 ones = ones8();
  attn_chunks(Kph, Vph, em, qa, lane, spl * SPLW, SPLW / 32, pbuf[wave], o0, o1, l, ones);
  float* Og = (float*)(ws + OFF_OG);
  float* Lg = (float*)(ws + OFF_LG);
#pragma unroll
  for (int r = 0; r < 16; ++r) {
    int row = (r & 3) + ((r >> 2) << 3) + (half_ << 2);
    int q = qbase + row;
    Og[(size_t)((spl * H_NUM + h) * 128 + q) * 64 + c]      = o0[r];
    Og[(size_t)((spl * H_NUM + h) * 128 + q) * 64 + 32 + c] = o1[r];
    if (c == 0) Lg[(spl * H_NUM + h) * 128 + q] = l[r];
  }
}

// ---------------- stage 2c: combine global partials (linear: sum o / sum l) ----------------
__global__ void combine_k(char* __restrict__ ws) {
  int idx = blockIdx.x * 256 + threadIdx.x;   // H*128*64 = 131072
  int h = idx >> 13, rem = idx & 8191, q = rem >> 6, d = rem & 63;
  const float* Og = (const float*)(ws + OFF_OG);
  const float* Lg = (const float*)(ws + OFF_LG);
  float o = 0.0f, l = 0.0f;
#pragma unroll
  for (int s = 0; s < NSPL; ++s) {
    o += Og[(size_t)((s * H_NUM + h) * 128 + q) * 64 + d];
    l += Lg[(s * H_NUM + h) * 128 + q];
  }
  int n = h * 64 + d;
  ((_Float16*)(ws + OFF_AOP))[((n >> 3) * R_TOT + q) * 8 + (n & 7)] = (_Float16)(o / l);
}

// ---------------- stage 3: output projection -> d_out (fp32) ----------------
__global__ __launch_bounds__(256) void out_gemm_k(char* __restrict__ ws, float* __restrict__ dout) {
  __shared__ __align__(16) _Float16 lds[2 * 8 * 128 * 8];
  const int m0 = blockIdx.y * 128;
  const int n0 = blockIdx.x * 128;
  floatx4 acc[4][4];
#pragma unroll
  for (int a = 0; a < 4; ++a)
#pragma unroll
    for (int b = 0; b < 4; ++b) acc[a][b] = zero4();
  gemm_tile((const _Float16*)(ws + OFF_AOP),
            (const _Float16*)(ws + OFF_WP + 3 * (size_t)SZ_WP1), m0, n0, lds, acc);
  const int lane = threadIdx.x & 63, wave = threadIdx.x >> 6;
  const int quad = lane >> 4, l16 = lane & 15;
  const int wm = (wave >> 1) * 64, wn = (wave & 1) * 64;
#pragma unroll
  for (int mt = 0; mt < 4; ++mt)
#pragma unroll
    for (int nt = 0; nt < 4; ++nt)
#pragma unroll
      for (int r = 0; r < 4; ++r) {
        int m = m0 + wm + mt * 16 + quad * 4 + r;
        int n = n0 + wn + nt * 16 + l16;
        float* p = (m < G_LEN) ? (dout + (size_t)S_LEN * E_DIM + (size_t)m * E_DIM + n)
                               : (dout + (size_t)(m - G_LEN) * E_DIM + n);
        *p = acc[mt][nt][r];
      }
}

extern "C" void kernel_launch(void* const* d_in, const int* in_sizes, int n_in,
                              void* d_out, int out_size, void* d_ws, size_t ws_size,
                              hipStream_t stream) {
  const float* tok  = (const float*)d_in[0];
  const float* glob = (const float*)d_in[1];
  const float* mask = (const float*)d_in[2];
  const float* Wq   = (const float*)d_in[3];
  const float* Wk   = (const float*)d_in[4];
  const float* Wv   = (const float*)d_in[5];
  const float* Wo   = (const float*)d_in[6];
  char*  ws   = (char*)d_ws;
  float* dout = (float*)d_out;

  pack_x_k<<<dim3((KBLK * R_TOT) / 256), dim3(256), 0, stream>>>(tok, glob, ws);
  pack_w_k<<<dim3((4 * KBLK * 1024 + R_TOT + 255) / 256), dim3(256), 0, stream>>>(Wq, Wk, Wv, Wo, mask, ws);
  qkv_gemm_k<<<dim3(8, 65, 3), dim3(256), 0, stream>>>(ws);
  local_attn_k<<<dim3(4, 16, 16), dim3(256), 0, stream>>>(ws);
  global_attn_k<<<dim3(NSPL, H_NUM), dim3(256), 0, stream>>>(ws);
  combine_k<<<dim3(512), dim3(256), 0, stream>>>(ws);
  out_gemm_k<<<dim3(8, 65), dim3(256), 0, stream>>>(ws, dout);
}

// Round 3
// 313.035 us; speedup vs baseline: 1.0685x; 1.0685x over previous
//
#include <hip/hip_runtime.h>
#include <stdint.h>

#define S_LEN  8192
#define G_LEN  128
#define E_DIM  1024
#define H_NUM  16
#define BS_LEN 512
#define R_TOT  8320          // G + S total rows
#define KBLK   128           // 1024/8 k-blocks
#define XBLK   1040          // R_TOT/8
#define NSPL   10            // global-attn key splits
#define SPLW   832           // keys per split (26 chunks of 32)

typedef _Float16 half8    __attribute__((ext_vector_type(8)));
typedef _Float16 half4    __attribute__((ext_vector_type(4)));
typedef float    floatx4  __attribute__((ext_vector_type(4)));
typedef float    floatx16 __attribute__((ext_vector_type(16)));

// Q scale = D^-0.5 * log2(e): exp(x) computed as exp2(x*log2e) with log2e folded into Q
#define QSCALE 0.18033688011112042f

// ---- workspace layout (bytes) ----
#define OFF_XP   0
#define OFF_AOP  0            // reuse: Xp dead after QKV GEMMs
#define OFF_WP   17039360
#define SZ_WP1   2097152
#define OFF_QP   25427968
#define OFF_KP   42467328
#define OFF_VP   59506688
#define OFF_FH   76546048     // f16 exp(mask) per key row, R_TOT entries
#define OFF_OG   76579328
#define OFF_LG   81822208

__device__ __forceinline__ floatx16 zero16() {
  floatx16 v;
#pragma unroll
  for (int i = 0; i < 16; ++i) v[i] = 0.0f;
  return v;
}
__device__ __forceinline__ floatx4 zero4() {
  floatx4 v;
#pragma unroll
  for (int i = 0; i < 4; ++i) v[i] = 0.0f;
  return v;
}

__device__ __forceinline__ void gl_lds16(const void* g, void* l) {
  __builtin_amdgcn_global_load_lds(
      (const __attribute__((address_space(1))) void*)g,
      (__attribute__((address_space(3))) void*)l, 16, 0, 0);
}

// pack two fp32 -> packed f16 pair (rtz), as int
__device__ __forceinline__ int pk_f16x2(float a, float b) {
  return __builtin_bit_cast(int, __builtin_amdgcn_cvt_pkrtz(a, b));
}

// ---------------- stage 0: pack X (f32 -> f16, k-block-packed) via LDS transpose ----------------
__global__ __launch_bounds__(256) void pack_x_k(const float* __restrict__ tok,
                                                const float* __restrict__ glob,
                                                char* __restrict__ ws) {
  __shared__ __align__(16) _Float16 tile[64 * 132];   // stride 132 -> 2-way (free) banks
  const int tid = threadIdx.x;
  const int r0 = blockIdx.y * 64;
  const int c0 = blockIdx.x * 128;
#pragma unroll
  for (int kk = 0; kk < 8; ++kk) {
    int f   = tid + kk * 256;       // 0..2047
    int row = f >> 5;               // 0..63
    int c4  = (f & 31) * 4;         // 0..124
    int r   = r0 + row;
    const float* src = (r < G_LEN) ? glob + (size_t)r * E_DIM
                                   : tok + (size_t)(r - G_LEN) * E_DIM;
    float4 v = *(const float4*)&src[c0 + c4];
    half4 h;
    h[0] = (_Float16)v.x; h[1] = (_Float16)v.y; h[2] = (_Float16)v.z; h[3] = (_Float16)v.w;
    *(half4*)&tile[row * 132 + c4] = h;
  }
  __syncthreads();
  _Float16* Xp = (_Float16*)(ws + OFF_XP);
#pragma unroll
  for (int uu = 0; uu < 4; ++uu) {
    int u    = tid + uu * 256;      // 0..1023
    int kb_l = u >> 6;              // 0..15
    int row  = u & 63;
    half4 a = *(const half4*)&tile[row * 132 + kb_l * 8];
    half4 b = *(const half4*)&tile[row * 132 + kb_l * 8 + 4];
    half8 o;
    o[0] = a[0]; o[1] = a[1]; o[2] = a[2]; o[3] = a[3];
    o[4] = b[0]; o[5] = b[1]; o[6] = b[2]; o[7] = b[3];
    int kb = (c0 >> 3) + kb_l;
    *(half8*)&Xp[((size_t)kb * R_TOT + r0 + row) * 8] = o;
  }
}

// -------- stage 0b: pack W (transposed, k-block-packed) + fh = exp(mask) --------
__global__ void pack_w_k(const float* __restrict__ Wq, const float* __restrict__ Wk,
                         const float* __restrict__ Wv, const float* __restrict__ Wo,
                         const float* __restrict__ mask, char* __restrict__ ws) {
  int t = blockIdx.x * 256 + threadIdx.x;
  const int NW = 4 * KBLK * 1024;
  if (t < NW) {
    int w   = t >> 17;
    int rem = t & 131071;
    int kb  = rem >> 10;
    int n   = rem & 1023;
    const float* W = (w == 0) ? Wq : (w == 1) ? Wk : (w == 2) ? Wv : Wo;
    half8 v;
#pragma unroll
    for (int j = 0; j < 8; ++j)
      v[j] = (_Float16)W[(size_t)(kb * 8 + j) * 1024 + n];
    *(half8*)(ws + OFF_WP + (size_t)w * SZ_WP1 + (size_t)(kb * 1024 + n) * 16) = v;
  } else {
    int t2 = t - NW;
    if (t2 < R_TOT) {
      _Float16* fh = (_Float16*)(ws + OFF_FH);
      float m = (t2 < G_LEN) ? 0.0f : mask[t2 - G_LEN];
      fh[t2] = (_Float16)__expf(m);
    }
  }
}

// ---------------- shared GEMM mainloop ----------------
template <bool SWAP>
__device__ __forceinline__ void gemm_tile(const _Float16* __restrict__ Ap,
                                          const _Float16* __restrict__ Bp,
                                          int m0, int n0, _Float16* lds,
                                          floatx4 acc[4][4]) {
  const int tid  = threadIdx.x;
  const int wave = tid >> 6;
  const int lane = tid & 63;
  const int quad = lane >> 4;
  const int l16  = lane & 15;
  _Float16* As = lds;
  _Float16* Bs = lds + 8 * 128 * 8;
  const int wm = (wave >> 1) * 64;
  const int wn = (wave & 1) * 64;
  for (int step = 0; step < 16; ++step) {
#pragma unroll
    for (int ui = 0; ui < 8; ++ui) {
      const int u   = wave * 8 + ui;
      const int isB = u >> 4;
      const int vv  = u & 15;
      const int kb  = vv >> 1;
      const int rh  = vv & 1;
      const _Float16* src =
          isB ? Bp + (size_t)((step * 8 + kb) * 1024 + n0 + rh * 64 + lane) * 8
              : Ap + (size_t)((step * 8 + kb) * R_TOT + m0 + rh * 64 + lane) * 8;
      _Float16* dst = (isB ? Bs : As) + (kb * 128 + rh * 64) * 8;
      gl_lds16(src, dst);
    }
    __syncthreads();
#pragma unroll
    for (int kk = 0; kk < 2; ++kk) {
      half8 af[4], bf[4];
#pragma unroll
      for (int mt = 0; mt < 4; ++mt)
        af[mt] = *(const half8*)(As + ((kk * 4 + quad) * 128 + wm + mt * 16 + l16) * 8);
#pragma unroll
      for (int nt = 0; nt < 4; ++nt)
        bf[nt] = *(const half8*)(Bs + ((kk * 4 + quad) * 128 + wn + nt * 16 + l16) * 8);
#pragma unroll
      for (int mt = 0; mt < 4; ++mt)
#pragma unroll
        for (int nt = 0; nt < 4; ++nt)
          acc[mt][nt] = SWAP
            ? __builtin_amdgcn_mfma_f32_16x16x32_f16(bf[nt], af[mt], acc[mt][nt], 0, 0, 0)
            : __builtin_amdgcn_mfma_f32_16x16x32_f16(af[mt], bf[nt], acc[mt][nt], 0, 0, 0);
    }
    __syncthreads();
  }
}

// ---------------- stage 1a: Q,K projections (swapped: acc = 4 consecutive n) ----------------
__global__ __launch_bounds__(256) void qk_gemm_k(char* __restrict__ ws) {
  __shared__ __align__(16) _Float16 lds[2 * 8 * 128 * 8];
  const int z  = blockIdx.z;      // 0=Q, 1=K
  const int m0 = blockIdx.y * 128;
  const int n0 = blockIdx.x * 128;
  floatx4 acc[4][4];
#pragma unroll
  for (int a = 0; a < 4; ++a)
#pragma unroll
    for (int b = 0; b < 4; ++b) acc[a][b] = zero4();
  gemm_tile<true>((const _Float16*)(ws + OFF_XP),
                  (const _Float16*)(ws + OFF_WP + (size_t)z * SZ_WP1), m0, n0, lds, acc);
  _Float16* dst = (_Float16*)(ws + (z == 0 ? OFF_QP : OFF_KP));
  const int lane = threadIdx.x & 63, wave = threadIdx.x >> 6;
  const int quad = lane >> 4, l16 = lane & 15;
  const int wm = (wave >> 1) * 64, wn = (wave & 1) * 64;
  const float scale = (z == 0) ? QSCALE : 1.0f;
#pragma unroll
  for (int mt = 0; mt < 4; ++mt)
#pragma unroll
    for (int nt = 0; nt < 4; ++nt) {
      int m  = m0 + wm + mt * 16 + l16;
      int nb = n0 + wn + nt * 16 + quad * 4;
      half4 h;
#pragma unroll
      for (int r = 0; r < 4; ++r) h[r] = (_Float16)(acc[mt][nt][r] * scale);
      int db = (nb >> 6) * 8 + ((nb & 63) >> 3);
      *(half4*)&dst[((size_t)db * R_TOT + m) * 8 + (nb & 7)] = h;
    }
}

// ---------------- stage 1b: V projection (normal order; scaled by fh[row]) ----------------
__global__ __launch_bounds__(256) void v_gemm_k(char* __restrict__ ws) {
  __shared__ __align__(16) _Float16 lds[2 * 8 * 128 * 8];
  const int m0 = blockIdx.y * 128;
  const int n0 = blockIdx.x * 128;
  floatx4 acc[4][4];
#pragma unroll
  for (int a = 0; a < 4; ++a)
#pragma unroll
    for (int b = 0; b < 4; ++b) acc[a][b] = zero4();
  gemm_tile<false>((const _Float16*)(ws + OFF_XP),
                   (const _Float16*)(ws + OFF_WP + 2 * (size_t)SZ_WP1), m0, n0, lds, acc);
  _Float16* dst = (_Float16*)(ws + OFF_VP);
  const _Float16* fh = (const _Float16*)(ws + OFF_FH);
  const int lane = threadIdx.x & 63, wave = threadIdx.x >> 6;
  const int quad = lane >> 4, l16 = lane & 15;
  const int wm = (wave >> 1) * 64, wn = (wave & 1) * 64;
#pragma unroll
  for (int mt = 0; mt < 4; ++mt)
#pragma unroll
    for (int nt = 0; nt < 4; ++nt) {
      int mb = m0 + wm + mt * 16 + quad * 4;
      int n  = n0 + wn + nt * 16 + l16;
      half4 fv = *(const half4*)&fh[mb];
      half4 h;
#pragma unroll
      for (int r = 0; r < 4; ++r) h[r] = (_Float16)(acc[mt][nt][r] * (float)fv[r]);
      *(half4*)&dst[(((size_t)(n >> 6) * XBLK + (mb >> 3)) * 64 + (n & 63)) * 8 + (mb & 7)] = h;
    }
}

// ---------------- fused attention core (LDS-free) ----------------
// S^T = mfma(Kfrag, Qfrag): lane holds col=q, regs = 16 key-rows. P=exp2(S).
// PV B-frag built in-register via packed-f16 shfl_xor(32). Mask folded into V'/f.
__device__ __forceinline__ void attn_chunks(const _Float16* __restrict__ Kph,
                                            const _Float16* __restrict__ Vph,
                                            const _Float16* __restrict__ fh,
                                            const half8 qa[4], int lane,
                                            int kbase0, int nch,
                                            floatx16& o0, floatx16& o1, floatx16& lacc) {
  const int  half_ = lane >> 5;
  const int  c     = lane & 31;
  const bool hb    = half_ != 0;
  for (int ci = 0; ci < nch; ++ci) {
    const int kb = kbase0 + ci * 32;
    floatx16 s = zero16();
#pragma unroll
    for (int ks = 0; ks < 4; ++ks) {
      half8 kfr = *(const half8*)&Kph[(size_t)((ks * 2 + half_) * R_TOT + kb + c) * 8];
      s = __builtin_amdgcn_mfma_f32_32x32x16_f16(kfr, qa[ks], s, 0, 0, 0);
    }
    int pk[8];
#pragma unroll
    for (int i = 0; i < 8; ++i) {
      float e0 = __builtin_amdgcn_exp2f(s[2 * i]);
      float e1 = __builtin_amdgcn_exp2f(s[2 * i + 1]);
      pk[i] = pk_f16x2(e0, e1);
    }
    int sw[8];
#pragma unroll
    for (int i = 0; i < 8; ++i) sw[i] = __shfl_xor(pk[i], 32);
    int4 bi0, bi1;
    bi0.x = hb ? sw[2] : pk[0];  bi0.y = hb ? sw[3] : pk[1];
    bi0.z = hb ? pk[2] : sw[0];  bi0.w = hb ? pk[3] : sw[1];
    bi1.x = hb ? sw[6] : pk[4];  bi1.y = hb ? sw[7] : pk[5];
    bi1.z = hb ? pk[6] : sw[4];  bi1.w = hb ? pk[7] : sw[5];
    half8 b0 = __builtin_bit_cast(half8, bi0);
    half8 b1 = __builtin_bit_cast(half8, bi1);
    // l accum: A-frag = f (exp(mask)) per key, row-independent
    half8 f0 = *(const half8*)&fh[kb + half_ * 8];
    half8 f1 = *(const half8*)&fh[kb + 16 + half_ * 8];
    lacc = __builtin_amdgcn_mfma_f32_32x32x16_f16(f0, b0, lacc, 0, 0, 0);
    lacc = __builtin_amdgcn_mfma_f32_32x32x16_f16(f1, b1, lacc, 0, 0, 0);
    // O^T accum: A-frag = V' (d rows)
    const int xb = kb >> 3;
    half8 vA0 = *(const half8*)&Vph[(size_t)((xb + half_) * 64 + c) * 8];
    half8 vA1 = *(const half8*)&Vph[(size_t)((xb + 2 + half_) * 64 + c) * 8];
    half8 vB0 = *(const half8*)&Vph[(size_t)((xb + half_) * 64 + 32 + c) * 8];
    half8 vB1 = *(const half8*)&Vph[(size_t)((xb + 2 + half_) * 64 + 32 + c) * 8];
    o0 = __builtin_amdgcn_mfma_f32_32x32x16_f16(vA0, b0, o0, 0, 0, 0);
    o0 = __builtin_amdgcn_mfma_f32_32x32x16_f16(vA1, b1, o0, 0, 0, 0);
    o1 = __builtin_amdgcn_mfma_f32_32x32x16_f16(vB0, b0, o1, 0, 0, 0);
    o1 = __builtin_amdgcn_mfma_f32_32x32x16_f16(vB1, b1, o1, 0, 0, 0);
  }
}

// ---------------- stage 2a: local attention ----------------
__global__ __launch_bounds__(256) void local_attn_k(char* __restrict__ ws) {
  const int wave = threadIdx.x >> 6, lane = threadIdx.x & 63;
  const int h = blockIdx.z, blk = blockIdx.y, qg = blockIdx.x;
  const int qbase = G_LEN + blk * BS_LEN + qg * 128 + wave * 32;
  const _Float16* Qph = (const _Float16*)(ws + OFF_QP) + (size_t)h * 8 * R_TOT * 8;
  const _Float16* Kph = (const _Float16*)(ws + OFF_KP) + (size_t)h * 8 * R_TOT * 8;
  const _Float16* Vph = (const _Float16*)(ws + OFF_VP) + (size_t)h * XBLK * 64 * 8;
  const _Float16* fh  = (const _Float16*)(ws + OFF_FH);
  const int half_ = lane >> 5, c = lane & 31;
  half8 qa[4];
#pragma unroll
  for (int ks = 0; ks < 4; ++ks)
    qa[ks] = *(const half8*)&Qph[(size_t)((ks * 2 + half_) * R_TOT + qbase + c) * 8];
  floatx16 o0 = zero16(), o1 = zero16(), l = zero16();
  attn_chunks(Kph, Vph, fh, qa, lane, 0, G_LEN / 32, o0, o1, l);
  attn_chunks(Kph, Vph, fh, qa, lane, G_LEN + blk * BS_LEN, BS_LEN / 32, o0, o1, l);
  _Float16* AOp = (_Float16*)(ws + OFF_AOP);
  const float inv = 1.0f / l[0];
  const int m = qbase + c;
#pragma unroll
  for (int g = 0; g < 4; ++g) {
    half4 ha, hc;
#pragma unroll
    for (int i = 0; i < 4; ++i) {
      ha[i] = (_Float16)(o0[4 * g + i] * inv);
      hc[i] = (_Float16)(o1[4 * g + i] * inv);
    }
    *(half4*)&AOp[((size_t)(h * 8 + g) * R_TOT + m) * 8 + 4 * half_] = ha;
    *(half4*)&AOp[((size_t)(h * 8 + 4 + g) * R_TOT + m) * 8 + 4 * half_] = hc;
  }
}

// ---------------- stage 2b: global attention (key-split partials) ----------------
__global__ __launch_bounds__(256) void global_attn_k(char* __restrict__ ws) {
  const int wave = threadIdx.x >> 6, lane = threadIdx.x & 63;
  const int spl = blockIdx.x, h = blockIdx.y;
  const int qbase = wave * 32;
  const _Float16* Qph = (const _Float16*)(ws + OFF_QP) + (size_t)h * 8 * R_TOT * 8;
  const _Float16* Kph = (const _Float16*)(ws + OFF_KP) + (size_t)h * 8 * R_TOT * 8;
  const _Float16* Vph = (const _Float16*)(ws + OFF_VP) + (size_t)h * XBLK * 64 * 8;
  const _Float16* fh  = (const _Float16*)(ws + OFF_FH);
  const int half_ = lane >> 5, c = lane & 31;
  half8 qa[4];
#pragma unroll
  for (int ks = 0; ks < 4; ++ks)
    qa[ks] = *(const half8*)&Qph[(size_t)((ks * 2 + half_) * R_TOT + qbase + c) * 8];
  floatx16 o0 = zero16(), o1 = zero16(), l = zero16();
  attn_chunks(Kph, Vph, fh, qa, lane, spl * SPLW, SPLW / 32, o0, o1, l);
  float* Og = (float*)(ws + OFF_OG);
  float* Lg = (float*)(ws + OFF_LG);
  const int q = qbase + c;
#pragma unroll
  for (int g = 0; g < 4; ++g) {
    float4 fa, fb;
    fa.x = o0[4 * g]; fa.y = o0[4 * g + 1]; fa.z = o0[4 * g + 2]; fa.w = o0[4 * g + 3];
    fb.x = o1[4 * g]; fb.y = o1[4 * g + 1]; fb.z = o1[4 * g + 2]; fb.w = o1[4 * g + 3];
    *(float4*)&Og[((size_t)(spl * H_NUM + h) * 128 + q) * 64 + 8 * g + 4 * half_] = fa;
    *(float4*)&Og[((size_t)(spl * H_NUM + h) * 128 + q) * 64 + 32 + 8 * g + 4 * half_] = fb;
  }
  if (half_ == 0) Lg[(spl * H_NUM + h) * 128 + q] = l[0];
}

// ---------------- stage 2c: combine global partials ----------------
__global__ void combine_k(char* __restrict__ ws) {
  int idx = blockIdx.x * 256 + threadIdx.x;   // H*128*64 = 131072
  int h = idx >> 13, rem = idx & 8191, q = rem >> 6, d = rem & 63;
  const float* Og = (const float*)(ws + OFF_OG);
  const float* Lg = (const float*)(ws + OFF_LG);
  float o = 0.0f, l = 0.0f;
#pragma unroll
  for (int s = 0; s < NSPL; ++s) {
    o += Og[(size_t)((s * H_NUM + h) * 128 + q) * 64 + d];
    l += Lg[(s * H_NUM + h) * 128 + q];
  }
  int n = h * 64 + d;
  ((_Float16*)(ws + OFF_AOP))[((size_t)(n >> 3) * R_TOT + q) * 8 + (n & 7)] = (_Float16)(o / l);
}

// ---------------- stage 3: output projection -> d_out (fp32, float4 stores) ----------------
__global__ __launch_bounds__(256) void out_gemm_k(char* __restrict__ ws, float* __restrict__ dout) {
  __shared__ __align__(16) _Float16 lds[2 * 8 * 128 * 8];
  const int m0 = blockIdx.y * 128;
  const int n0 = blockIdx.x * 128;
  floatx4 acc[4][4];
#pragma unroll
  for (int a = 0; a < 4; ++a)
#pragma unroll
    for (int b = 0; b < 4; ++b) acc[a][b] = zero4();
  gemm_tile<true>((const _Float16*)(ws + OFF_AOP),
                  (const _Float16*)(ws + OFF_WP + 3 * (size_t)SZ_WP1), m0, n0, lds, acc);
  const int lane = threadIdx.x & 63, wave = threadIdx.x >> 6;
  const int quad = lane >> 4, l16 = lane & 15;
  const int wm = (wave >> 1) * 64, wn = (wave & 1) * 64;
#pragma unroll
  for (int mt = 0; mt < 4; ++mt)
#pragma unroll
    for (int nt = 0; nt < 4; ++nt) {
      int m  = m0 + wm + mt * 16 + l16;
      int nb = n0 + wn + nt * 16 + quad * 4;
      float4 f4;
      f4.x = acc[mt][nt][0]; f4.y = acc[mt][nt][1];
      f4.z = acc[mt][nt][2]; f4.w = acc[mt][nt][3];
      float* p = (m < G_LEN) ? (dout + (size_t)S_LEN * E_DIM + (size_t)m * E_DIM + nb)
                             : (dout + (size_t)(m - G_LEN) * E_DIM + nb);
      *(float4*)p = f4;
    }
}

extern "C" void kernel_launch(void* const* d_in, const int* in_sizes, int n_in,
                              void* d_out, int out_size, void* d_ws, size_t ws_size,
                              hipStream_t stream) {
  const float* tok  = (const float*)d_in[0];
  const float* glob = (const float*)d_in[1];
  const float* mask = (const float*)d_in[2];
  const float* Wq   = (const float*)d_in[3];
  const float* Wk   = (const float*)d_in[4];
  const float* Wv   = (const float*)d_in[5];
  const float* Wo   = (const float*)d_in[6];
  char*  ws   = (char*)d_ws;
  float* dout = (float*)d_out;

  pack_x_k<<<dim3(8, 130), dim3(256), 0, stream>>>(tok, glob, ws);
  pack_w_k<<<dim3((4 * KBLK * 1024 + R_TOT + 255) / 256), dim3(256), 0, stream>>>(Wq, Wk, Wv, Wo, mask, ws);
  qk_gemm_k<<<dim3(8, 65, 2), dim3(256), 0, stream>>>(ws);
  v_gemm_k<<<dim3(8, 65), dim3(256), 0, stream>>>(ws);
  local_attn_k<<<dim3(4, 16, 16), dim3(256), 0, stream>>>(ws);
  global_attn_k<<<dim3(NSPL, H_NUM), dim3(256), 0, stream>>>(ws);
  combine_k<<<dim3(512), dim3(256), 0, stream>>>(ws);
  out_gemm_k<<<dim3(8, 65), dim3(256), 0, stream>>>(ws, dout);
}